// Round 12
// baseline (335.452 us; speedup 1.0000x reference)
//
#include <hip/hip_runtime.h>
#include <hip/hip_bf16.h>

#define VV 100000
#define EE 50
#define HH 64
#define BB 1024
#define TT 200
// 3H = 192

typedef float v4f __attribute__((ext_vector_type(4)));
typedef float f32x4 __attribute__((ext_vector_type(4)));
typedef short bf16x8 __attribute__((ext_vector_type(8)));
typedef _Float16 f16x8 __attribute__((ext_vector_type(8)));

__device__ __forceinline__ float fsig(float x) {
    return 1.f / (1.f + __expf(-x));
}
__device__ __forceinline__ float ftanh(float x) {
    float e = __expf(2.f * x);
    return 1.f - 2.f / (e + 1.f);
}
// fp32 -> bf16 round-to-nearest-even (values are tame: no NaN/Inf handling needed)
__device__ __forceinline__ short f2bf(float f) {
    union { float f; unsigned u; } v; v.f = f;
    unsigned r = v.u + 0x7FFFu + ((v.u >> 16) & 1u);
    return (short)(r >> 16);
}

// ---------------- Kernel A: embW[v][c] = emb[v][:] @ Wx[:,c] + bi[c]  (both dirs via blockIdx.y) ----------------
__global__ __launch_bounds__(256) void embw_kernel(
    const float* __restrict__ emb,
    const float* __restrict__ Wx_f, const float* __restrict__ bi_f,
    const float* __restrict__ Wx_b, const float* __restrict__ bi_b,
    float* __restrict__ embW_f, float* __restrict__ embW_b)
{
    const float* Wx = blockIdx.y ? Wx_b : Wx_f;
    const float* bi = blockIdx.y ? bi_b : bi_f;
    float* embW     = blockIdx.y ? embW_b : embW_f;
    __shared__ float wx_lds[EE * 192];
    __shared__ float emb_lds[32 * EE];
    const int tid = threadIdx.x;
    const int v0 = blockIdx.x * 32;
    for (int i = tid; i < EE * 192; i += 256) wx_lds[i] = Wx[i];
    for (int i = tid; i < 32 * EE; i += 256) emb_lds[i] = emb[(size_t)v0 * EE + i];
    __syncthreads();
    const int cg = tid & 63;
    const int rg = tid >> 6;
    float acc[8][3];
    #pragma unroll
    for (int i = 0; i < 8; i++) {
        acc[i][0] = bi[cg];
        acc[i][1] = bi[cg + 64];
        acc[i][2] = bi[cg + 128];
    }
    for (int k = 0; k < EE; k++) {
        const float wx0 = wx_lds[k * 192 + cg];
        const float wx1 = wx_lds[k * 192 + cg + 64];
        const float wx2 = wx_lds[k * 192 + cg + 128];
        #pragma unroll
        for (int i = 0; i < 8; i++) {
            const float ev = emb_lds[(rg * 8 + i) * EE + k];
            acc[i][0] = fmaf(ev, wx0, acc[i][0]);
            acc[i][1] = fmaf(ev, wx1, acc[i][1]);
            acc[i][2] = fmaf(ev, wx2, acc[i][2]);
        }
    }
    #pragma unroll
    for (int i = 0; i < 8; i++) {
        const size_t row = (size_t)(v0 + rg * 8 + i) * 192;
        embW[row + cg]       = acc[i][0];
        embW[row + cg + 64]  = acc[i][1];
        embW[row + cg + 128] = acc[i][2];
    }
}

// ---------------- Kernel B v9: MFMA GRU + LDS-windowed gx staging (counted vmcnt) ----------------
// Block = 256 thr (4 waves) per (16 seqs, dir). gx = embW[ids] staged 2 steps ahead into a
// 3-slot LDS window via global_load_lds (fire-and-forget); step end = s_waitcnt vmcnt(16)
// lgkmcnt(0) + s_barrier (per-step vmem ops = 4 stores + 12 stage loads -> 16 = exactly one
// step of slack; in-order vmcnt semantics make this safe even with extra compiler vmem ops).
// hlds is XOR-swizzled (chunk ^= row&7, 128B rows) -> conflict-free ds_read_b128 A-frags.
// Fragment maps identical to gru8 (HW-verified): A row=l15, k=8*lhi+j; C/D col=l15, row=4*lhi+reg.
__global__ __launch_bounds__(256, 1) void gru9_kernel(
    const int* __restrict__ ids,
    const float* __restrict__ embW_f, const float* __restrict__ embW_b,
    const float* __restrict__ Wh_f, const float* __restrict__ br_f,
    const float* __restrict__ Wh_b, const float* __restrict__ br_b,
    float* __restrict__ outb,     // [B, T, 128]
    float* __restrict__ hf_out)   // [B, 64]
{
    const int tid  = threadIdx.x;
    const int w    = tid >> 6;
    const int lane = tid & 63;
    const int l15  = lane & 15;
    const int lhi  = lane >> 4;
    const int dir  = blockIdx.y;
    const int b0   = blockIdx.x * 16;
    const float* eW = dir ? embW_b : embW_f;
    const float* Wh = dir ? Wh_b : Wh_f;
    const float* br = dir ? br_b : br_f;
    const int c = 16 * w + l15;   // hidden column 0..63 owned by this lane

    // B-fragments: gate g (0=z,1=r,2=n), k-tile kt. Element jj: k = 32*kt + 8*lhi + jj, col = 64*g + c.
    f16x8 bw[3][2];
    #pragma unroll
    for (int g = 0; g < 3; g++) {
        #pragma unroll
        for (int kt = 0; kt < 2; kt++) {
            #pragma unroll
            for (int jj = 0; jj < 8; jj++)
                bw[g][kt][jj] = (_Float16)Wh[(size_t)(32 * kt + 8 * lhi + jj) * 192 + 64 * g + c];
        }
    }
    const float brz = br[c], brr = br[64 + c], brn = br[128 + c];

    __shared__ float gx_s[3][16 * 193];               // 37056 B: 3-slot gx window, 193-f32 seq stride
    __shared__ __align__(16) char hbuf[2][2048];      // h as f16, swizzled: row*128 + ((col>>3)^(row&7))*16 + (col&7)*2
    __shared__ int ids_s[16 * TT];                    // 12800 B
    for (int i = tid; i < 16 * TT; i += 256) ids_s[i] = ids[(size_t)b0 * TT + i];
    for (int i = tid; i < 1024; i += 256) ((unsigned*)hbuf)[i] = 0u;
    float hold[4] = {0.f, 0.f, 0.f, 0.f};             // h[4*lhi+r][c], fp32 master copy
    __syncthreads();

    const int t0 = dir ? (TT - 1) : 0;
    const int dt = dir ? -1 : 1;

    // stage gx for time tf into slot sl: wave w stages seqs 4w..4w+3 (12 global_load_lds/wave)
    #define STAGE(sl, tf)                                                                     \
        {                                                                                     \
            _Pragma("unroll")                                                                 \
            for (int q = 0; q < 4; q++) {                                                     \
                const int seqq = 4 * w + q;                                                   \
                const int idq = ids_s[seqq * TT + (tf)];                                      \
                const float* srcb = eW + (size_t)idq * 192;                                   \
                _Pragma("unroll")                                                             \
                for (int p = 0; p < 3; p++) {                                                 \
                    __builtin_amdgcn_global_load_lds(                                         \
                        (const __attribute__((address_space(1))) void*)(srcb + p * 64 + lane),\
                        (__attribute__((address_space(3))) void*)(&gx_s[sl][seqq * 193 + p * 64]), \
                        4, 0, 0);                                                             \
                }                                                                             \
            }                                                                                 \
        }

    // prologue: stage steps 0 and 1 into slots 0 and 1
    STAGE(0, t0)
    STAGE(1, t0 + dt)
    __syncthreads();   // drains vmcnt(0): slots 0,1 ready

    int slot = 0;      // slot of current step s (s % 3)
    int wslot = 2;     // slot to stage into ((s+2) % 3)
    int cur = 0;

    for (int s = 0; s < TT; s++) {
        const int t = t0 + s * dt;
        // gx + ids for this lane's 4 rows (from LDS)
        int idv[4];
        float gxv[3][4];
        #pragma unroll
        for (int r = 0; r < 4; r++) {
            idv[r] = ids_s[(4 * lhi + r) * TT + t];
            const float* base = &gx_s[slot][(4 * lhi + r) * 193 + c];
            gxv[0][r] = base[0];
            gxv[1][r] = base[64];
            gxv[2][r] = base[128];
        }
        // A-fragments (swizzled, conflict-free b128): row l15, chunks lhi and lhi+4
        const f16x8 a0 = *(const f16x8*)(hbuf[cur] + l15 * 128 + ((lhi ^ (l15 & 7)) << 4));
        const f16x8 a1 = *(const f16x8*)(hbuf[cur] + l15 * 128 + (((lhi + 4) ^ (l15 & 7)) << 4));
        // 6 MFMA: gh for the 3 gates over K=64
        f32x4 az = {0.f, 0.f, 0.f, 0.f};
        f32x4 ar = {0.f, 0.f, 0.f, 0.f};
        f32x4 an = {0.f, 0.f, 0.f, 0.f};
        az = __builtin_amdgcn_mfma_f32_16x16x32_f16(a0, bw[0][0], az, 0, 0, 0);
        ar = __builtin_amdgcn_mfma_f32_16x16x32_f16(a0, bw[1][0], ar, 0, 0, 0);
        an = __builtin_amdgcn_mfma_f32_16x16x32_f16(a0, bw[2][0], an, 0, 0, 0);
        az = __builtin_amdgcn_mfma_f32_16x16x32_f16(a1, bw[0][1], az, 0, 0, 0);
        ar = __builtin_amdgcn_mfma_f32_16x16x32_f16(a1, bw[1][1], ar, 0, 0, 0);
        an = __builtin_amdgcn_mfma_f32_16x16x32_f16(a1, bw[2][1], an, 0, 0, 0);
        // gates + h update for rows 4*lhi+r
        const int nxt = cur ^ 1;
        #pragma unroll
        for (int r = 0; r < 4; r++) {
            const float z  = fsig(gxv[0][r] + az[r] + brz);
            const float rg = fsig(gxv[1][r] + ar[r] + brr);
            const float hh = ftanh(gxv[2][r] + rg * (an[r] + brn));
            float hnew = z * hold[r] + (1.f - z) * hh;
            hnew = (idv[r] != 0) ? hnew : hold[r];
            hold[r] = hnew;
            const int row = 4 * lhi + r;
            const int wb = row * 128 + ((((c >> 3) ^ (row & 7))) << 4) + ((c & 7) << 1);
            *(_Float16*)(hbuf[nxt] + wb) = (_Float16)hnew;
            outb[((size_t)(b0 + row) * TT + t) * 128 + dir * 64 + c] = hnew;
        }
        cur = nxt;
        // stage step s+2 (fire-and-forget; lands in wslot which was read at step s-1)
        if (s + 2 < TT) STAGE(wslot, t + 2 * dt)
        // counted waits: leave the newest 16 vmem ops (this step's 4 stores + 12 stage loads)
        // in flight across the barrier; drain LDS (h writes + gx/ids reads).
        asm volatile("s_waitcnt vmcnt(16) lgkmcnt(0)\n\ts_barrier" ::: "memory");
        __builtin_amdgcn_sched_barrier(0);
        // rotate slots
        slot = (slot == 2) ? 0 : slot + 1;
        wslot = (wslot == 2) ? 0 : wslot + 1;
    }
    if (dir == 0) {
        #pragma unroll
        for (int r = 0; r < 4; r++)
            hf_out[(size_t)(b0 + 4 * lhi + r) * 64 + c] = hold[r];
    }
    #undef STAGE
}

// ---------------- Kernel C v7: MFMA keys GEMM ----------------
#define NTILE 13   // ceil(200/16)

__global__ __launch_bounds__(256) void attn7_kernel(
    const int* __restrict__ ids,
    const float* __restrict__ outb,   // [B,T,128] fp32
    const float* __restrict__ hf,     // [B,64]
    const float* __restrict__ Wk, const float* __restrict__ bk,
    const float* __restrict__ Wq, const float* __restrict__ bq,
    const float* __restrict__ We, const float* __restrict__ be,
    float* __restrict__ ctx)          // [B,128]
{
    __shared__ __align__(16) short wk_sw[1024 * 8];  // [slot][j]; slot = ks*256 + lhi*64 + nt*16 + l15
    __shared__ float q_lds[64];
    __shared__ float we_lds[64];
    __shared__ float e_lds[TT];
    __shared__ float part[4][128];
    const int b = blockIdx.x;
    const int tid = threadIdx.x;
    const int w = tid >> 6;
    const int lane = tid & 63;
    const int l15 = lane & 15;
    const int lhi = lane >> 4;

    // Stage Wk (fp32 -> bf16) into fragment-ordered LDS. Each thread fills 4 slots of 8 values.
    #pragma unroll
    for (int i = 0; i < 4; i++) {
        const int slot = tid + 256 * i;
        const int s_l15 = slot & 15;
        const int s_nt  = (slot >> 4) & 3;
        const int s_lhi = (slot >> 6) & 3;
        const int s_ks  = slot >> 8;
        const int kbase = 32 * s_ks + 8 * s_lhi;
        const int col   = 16 * s_nt + s_l15;
        bf16x8 v;
        #pragma unroll
        for (int jj = 0; jj < 8; jj++) v[jj] = f2bf(Wk[(size_t)(kbase + jj) * 64 + col]);
        *(bf16x8*)&wk_sw[slot * 8] = v;
    }
    // q[c] = bq[c] + hf[b] @ Wq[:,c] (wave 0; coalesced column reads)
    if (tid < 64) {
        float qc = bq[tid];
        const float* hfb = hf + (size_t)b * 64;
        for (int k = 0; k < 64; k++) qc = fmaf(hfb[k], Wq[k * 64 + tid], qc);
        q_lds[tid] = qc;
        we_lds[tid] = We[tid];
    }
    __syncthreads();

    // keys + energy, 16-row tiles round-robined over the 4 waves
    for (int tile = w; tile < NTILE; tile += 4) {
        const int t0 = tile * 16;
        const int t = t0 + l15;
        f32x4 acc[4];
        #pragma unroll
        for (int nt = 0; nt < 4; nt++) { acc[nt][0] = 0.f; acc[nt][1] = 0.f; acc[nt][2] = 0.f; acc[nt][3] = 0.f; }
        #pragma unroll
        for (int ks = 0; ks < 4; ks++) {
            bf16x8 a;
            if (t < TT) {
                const float* p = outb + ((size_t)b * TT + t) * 128 + 32 * ks + 8 * lhi;
                const float4 lo = *(const float4*)p;
                const float4 hi = *(const float4*)(p + 4);
                a[0] = f2bf(lo.x); a[1] = f2bf(lo.y); a[2] = f2bf(lo.z); a[3] = f2bf(lo.w);
                a[4] = f2bf(hi.x); a[5] = f2bf(hi.y); a[6] = f2bf(hi.z); a[7] = f2bf(hi.w);
            } else {
                #pragma unroll
                for (int jj = 0; jj < 8; jj++) a[jj] = 0;
            }
            #pragma unroll
            for (int nt = 0; nt < 4; nt++) {
                const bf16x8 bf = *(const bf16x8*)&wk_sw[(ks * 256 + lhi * 64 + nt * 16 + l15) * 8];
                acc[nt] = __builtin_amdgcn_mfma_f32_16x16x32_bf16(a, bf, acc[nt], 0, 0, 0);
            }
        }
        // energy partials: ep[r] = sum_c We[c] * tanh(keys[t0+4*lhi+r][c] + q[c]); c spread over l15 x nt
        float ep0 = 0.f, ep1 = 0.f, ep2 = 0.f, ep3 = 0.f;
        #pragma unroll
        for (int nt = 0; nt < 4; nt++) {
            const int c = 16 * nt + l15;
            const float qn = q_lds[c];
            const float wen = we_lds[c];
            ep0 = fmaf(wen, ftanh(acc[nt][0] + qn), ep0);
            ep1 = fmaf(wen, ftanh(acc[nt][1] + qn), ep1);
            ep2 = fmaf(wen, ftanh(acc[nt][2] + qn), ep2);
            ep3 = fmaf(wen, ftanh(acc[nt][3] + qn), ep3);
        }
        #pragma unroll
        for (int off = 1; off < 16; off <<= 1) {
            ep0 += __shfl_xor(ep0, off);
            ep1 += __shfl_xor(ep1, off);
            ep2 += __shfl_xor(ep2, off);
            ep3 += __shfl_xor(ep3, off);
        }
        if (l15 == 0) {
            const int rbase = t0 + 4 * lhi;
            if (rbase + 0 < TT) e_lds[rbase + 0] = ep0;
            if (rbase + 1 < TT) e_lds[rbase + 1] = ep1;
            if (rbase + 2 < TT) e_lds[rbase + 2] = ep2;
            if (rbase + 3 < TT) e_lds[rbase + 3] = ep3;
        }
    }
    __syncthreads();
    // softmax over t (wave 0)
    if (w == 0) {
        const float bev = be[0];
        for (int t = lane; t < TT; t += 64) {
            float e = e_lds[t] + bev;
            if (ids[(size_t)b * TT + t] == 0) e -= 1e9f;
            e_lds[t] = e;
        }
        float m = -1e30f;
        for (int t = lane; t < TT; t += 64) m = fmaxf(m, e_lds[t]);
        #pragma unroll
        for (int off = 32; off > 0; off >>= 1) m = fmaxf(m, __shfl_xor(m, off));
        float ssum = 0.f;
        for (int t = lane; t < TT; t += 64) { const float v = __expf(e_lds[t] - m); e_lds[t] = v; ssum += v; }
        #pragma unroll
        for (int off = 32; off > 0; off >>= 1) ssum += __shfl_xor(ssum, off);
        const float inv = 1.f / ssum;
        for (int t = lane; t < TT; t += 64) e_lds[t] *= inv;
    }
    __syncthreads();
    // context (fp32): wave w covers t ≡ w (mod 4)
    float c0 = 0.f, c1 = 0.f;
    for (int t = w; t < TT; t += 4) {
        const float* orow = outb + ((size_t)b * TT + t) * 128;
        const float wt = e_lds[t];
        c0 = fmaf(wt, orow[lane], c0);
        c1 = fmaf(wt, orow[64 + lane], c1);
    }
    part[w][lane] = c0;
    part[w][64 + lane] = c1;
    __syncthreads();
    if (tid < 128)
        ctx[(size_t)b * 128 + tid] = part[0][tid] + part[1][tid] + part[2][tid] + part[3][tid];
}

// ---------------- (fallback) GRU 3-wave kernel, recompute-gx variant ----------------
template<bool USE_EMBW>
__global__ __launch_bounds__(192, 2) void gru_kernel(
    const int* __restrict__ ids,
    const float* __restrict__ embW_f, const float* __restrict__ embW_b,
    const float* __restrict__ emb,
    const float* __restrict__ Wx_f, const float* __restrict__ bi_f,
    const float* __restrict__ Wx_b, const float* __restrict__ bi_b,
    const float* __restrict__ Wh_f, const float* __restrict__ br_f,
    const float* __restrict__ Wh_b, const float* __restrict__ br_b,
    float* __restrict__ outb, float* __restrict__ hf_out)
{
    constexpr int R = 4;
    __shared__ float h_lds[R][64];
    __shared__ float rg_lds[R][64];
    __shared__ float hh_lds[R][64];
    __shared__ int ids_lds[R * TT];
    const int tid = threadIdx.x;
    const int w = tid >> 6;
    const int j = tid & 63;
    const int dir = blockIdx.y;
    const int b0 = blockIdx.x * R;
    const float* embW = dir ? embW_b : embW_f;
    const float* Wh   = dir ? Wh_b : Wh_f;
    const float* br   = dir ? br_b : br_f;
    const float* Wx   = dir ? Wx_b : Wx_f;
    const float* bi   = dir ? bi_b : bi_f;
    const int c = w * 64 + j;

    float whc[64];
    #pragma unroll
    for (int k = 0; k < 64; k++) whc[k] = Wh[k * 192 + c];
    const float brc = br[c];
    float wxc[EE];
    float bic = 0.f;
    if (!USE_EMBW) {
        #pragma unroll
        for (int k = 0; k < EE; k++) wxc[k] = Wx[k * 192 + c];
        bic = bi[c];
    }
    for (int i = tid; i < R * TT; i += 192) ids_lds[i] = ids[(size_t)b0 * TT + i];
    if (w == 0) {
        #pragma unroll
        for (int r = 0; r < R; r++) h_lds[r][j] = 0.f;
    }
    __syncthreads();

    for (int s = 0; s < TT; s++) {
        const int t = dir ? (TT - 1 - s) : s;
        int idv[R];
        float gxv[R], accv[R];
        #pragma unroll
        for (int r = 0; r < R; r++) idv[r] = ids_lds[r * TT + t];
        if (USE_EMBW) {
            #pragma unroll
            for (int r = 0; r < R; r++) gxv[r] = embW[(size_t)idv[r] * 192 + c];
        } else {
            #pragma unroll
            for (int r = 0; r < R; r++) {
                float acc = bic;
                const float* er = emb + (size_t)idv[r] * EE;
                #pragma unroll
                for (int k = 0; k < EE; k++) acc = fmaf(er[k], wxc[k], acc);
                gxv[r] = acc;
            }
        }
        #pragma unroll
        for (int r = 0; r < R; r++) {
            float acc = brc;
            const float4* h4 = (const float4*)(&h_lds[r][0]);
            #pragma unroll
            for (int k4 = 0; k4 < 16; k4++) {
                const float4 hv = h4[k4];
                acc = fmaf(hv.x, whc[4 * k4 + 0], acc);
                acc = fmaf(hv.y, whc[4 * k4 + 1], acc);
                acc = fmaf(hv.z, whc[4 * k4 + 2], acc);
                acc = fmaf(hv.w, whc[4 * k4 + 3], acc);
            }
            accv[r] = acc;
        }
        float zg[R] = {};
        if (w == 1) {
            #pragma unroll
            for (int r = 0; r < R; r++) rg_lds[r][j] = fsig(gxv[r] + accv[r]);
        } else if (w == 0) {
            #pragma unroll
            for (int r = 0; r < R; r++) zg[r] = fsig(gxv[r] + accv[r]);
        }
        __syncthreads();
        if (w == 2) {
            #pragma unroll
            for (int r = 0; r < R; r++)
                hh_lds[r][j] = ftanh(gxv[r] + rg_lds[r][j] * accv[r]);
        }
        __syncthreads();
        if (w == 0) {
            #pragma unroll
            for (int r = 0; r < R; r++) {
                const float hold = h_lds[r][j];
                float hnew = hold;
                if (idv[r] != 0) {
                    const float hh = hh_lds[r][j];
                    hnew = zg[r] * hold + (1.f - zg[r]) * hh;
                }
                h_lds[r][j] = hnew;
                outb[((size_t)(b0 + r) * TT + t) * 128 + dir * 64 + j] = hnew;
            }
        }
        __syncthreads();
    }
    if (dir == 0 && w == 0) {
        #pragma unroll
        for (int r = 0; r < R; r++) hf_out[(size_t)(b0 + r) * 64 + j] = h_lds[r][j];
    }
}

extern "C" void kernel_launch(void* const* d_in, const int* in_sizes, int n_in,
                              void* d_out, int out_size, void* d_ws, size_t ws_size,
                              hipStream_t stream) {
    const int*   ids  = (const int*)d_in[0];
    const float* emb  = (const float*)d_in[1];
    const float* Wx_f = (const float*)d_in[2];
    const float* Wh_f = (const float*)d_in[3];
    const float* bi_f = (const float*)d_in[4];
    const float* br_f = (const float*)d_in[5];
    const float* Wx_b = (const float*)d_in[6];
    const float* Wh_b = (const float*)d_in[7];
    const float* bi_b = (const float*)d_in[8];
    const float* br_b = (const float*)d_in[9];
    const float* Wk   = (const float*)d_in[10];
    const float* bk   = (const float*)d_in[11];
    const float* Wq   = (const float*)d_in[12];
    const float* bq   = (const float*)d_in[13];
    const float* We   = (const float*)d_in[14];
    const float* be   = (const float*)d_in[15];
    float* ctx = (float*)d_out;

    float* ws = (float*)d_ws;
    const size_t embw_elems = (size_t)VV * 192;
    const size_t out_elems  = (size_t)BB * TT * 128;
    const size_t hf_elems   = (size_t)BB * 64;
    const size_t need_embw  = (2 * embw_elems + out_elems + hf_elems) * sizeof(float);
    const bool use_embw = (ws_size >= need_embw);

    float *embW_f = nullptr, *embW_b = nullptr, *outb, *hf;
    if (use_embw) {
        embW_f = ws;
        embW_b = embW_f + embw_elems;
        outb   = embW_b + embw_elems;
        hf     = outb + out_elems;
    } else {
        outb = ws;
        hf   = outb + out_elems;
    }

    if (use_embw) {
        embw_kernel<<<dim3(VV / 32, 2), 256, 0, stream>>>(
            emb, Wx_f, bi_f, Wx_b, bi_b, embW_f, embW_b);
        gru9_kernel<<<dim3(BB / 16, 2), 256, 0, stream>>>(
            ids, embW_f, embW_b, Wh_f, br_f, Wh_b, br_b, outb, hf);
    } else {
        gru_kernel<false><<<dim3(BB / 4, 2), 192, 0, stream>>>(
            ids, embW_f, embW_b, emb, Wx_f, bi_f, Wx_b, bi_b,
            Wh_f, br_f, Wh_b, br_b, outb, hf);
    }
    attn7_kernel<<<BB, 256, 0, stream>>>(ids, outb, hf, Wk, bk, Wq, bq, We, be, ctx);
}